// Round 3
// baseline (30.582 us; speedup 1.0000x reference)
//
#include <hip/hip_runtime.h>

// PCEN [1, F=1024, T=16384] fp32.
// EMA with S=0.5 decays 2^-k -> 16-sample warmup window: abs error <= 2^-17,
// far under tolerance. R3: same LDS-transpose structure as R2 but C=16 ->
// LDS 16.4 KB/block -> 8 blocks/CU -> 32 waves/CU (100% occupancy).

static constexpr int F = 1024;
static constexpr int T = 16384;
static constexpr int C = 16;             // time chunk (= warmup window) per thread
static constexpr int BLOCK = 256;
static constexpr int HALF = BLOCK * C;   // 4096 floats per block (quarter row)
static constexpr int TPB = T / HALF;     // 4 tiles per row
static constexpr int SEEDQ = C / 4;      // 4 float4 of seed prefix
static constexpr int NQ = HALF / 4 + SEEDQ;  // 1028 float4 = 16.45 KB LDS
static constexpr int QPT = C / 4;        // 4 float4 per thread
static constexpr float EPS = 1e-6f;

// XOR bank-swizzle on float4 index: involution, touches only bits 0-2.
// For stride-4 and stride-1 wave accesses, every 16-lane group covers each
// bank-quad (q%8) exactly twice -> conflict-free ds_read/write_b128.
__device__ __forceinline__ int swz(int q) { return q ^ ((q >> 3) & 7); }

__device__ __forceinline__ void async_ld16(const float4* g, float4* l) {
  __builtin_amdgcn_global_load_lds(
      (const __attribute__((address_space(1))) void*)g,
      (__attribute__((address_space(3))) void*)l, 16, 0, 0);
}

__global__ __launch_bounds__(BLOCK) void pcen_kernel(
    const float* __restrict__ data,
    const float* __restrict__ alpha_p,
    const float* __restrict__ r_p,
    const float* __restrict__ delta_p,
    float* __restrict__ out)
{
  __shared__ float4 lds4[NQ];

  const int tid = threadIdx.x;
  const int bid = blockIdx.x;
  const int f = bid >> 2;                 // row       (TPB == 4)
  const int h = bid & (TPB - 1);          // tile in row
  const size_t base = (size_t)f * T + (size_t)h * HALF;
  const float4* __restrict__ g4 = reinterpret_cast<const float4*>(data + base);
  float4* __restrict__ o4 = reinterpret_cast<float4*>(out + base);

  // ---- stage global -> LDS: linear LDS dest, swizzle-inverse global src ----
  // LDS slot s holds logical element swz(s)  (swz is an involution).
  {
    const int wavebase = tid & ~63;       // wave-uniform base (+lane*16 by HW)
    #pragma unroll
    for (int i = 0; i < QPT; ++i) {
      const int p = SEEDQ + i * BLOCK + tid;
      async_ld16(g4 + (swz(p) - SEEDQ), &lds4[SEEDQ + i * BLOCK + wavebase]);
    }
    if (tid < SEEDQ) {
      if (h) {
        async_ld16(g4 - SEEDQ + tid, &lds4[0]);       // swz(q)==q for q<8
      } else {
        lds4[tid] = make_float4(0.f, 0.f, 0.f, 0.f);  // row start: EMA from 0
      }
    }
  }
  __syncthreads();   // drains vmcnt (global_load_lds) + lgkmcnt

  const float alpha = alpha_p[0];
  const float r     = r_p[0];
  const float delta = delta_p[0];
  const bool  rhalf = (r == 0.5f);
  const float delta_r = rhalf ? sqrtf(delta) : exp2f(r * log2f(delta));

  const int tq = tid * QPT;

  // ---- seed: EMA over previous 16 samples from m=0 (error <= 2^-17) ----
  float m = 0.0f;
  #pragma unroll
  for (int k = 0; k < QPT; ++k) {
    float4 v = lds4[swz(tq + k)];
    m = 0.5f * (m + v.x);
    m = 0.5f * (m + v.y);
    m = 0.5f * (m + v.z);
    m = 0.5f * (m + v.w);
  }

  // ---- main chunk: recurrence + pointwise PCEN into registers ----
  float4 res[QPT];

  #define PCEN_ELEM(XX, OO, POW)                        \
    { m = 0.5f * (m + (XX));                            \
      float lgm = log2f(m + EPS);                       \
      float inv = exp2f(-alpha * lgm);  /* (M+e)^-a */  \
      float qq  = fmaf((XX), inv, delta);               \
      OO = (POW) - delta_r; }

  if (rhalf) {
    #pragma unroll
    for (int k = 0; k < QPT; ++k) {
      float4 v = lds4[swz(SEEDQ + tq + k)];
      float4 o;
      PCEN_ELEM(v.x, o.x, sqrtf(qq));
      PCEN_ELEM(v.y, o.y, sqrtf(qq));
      PCEN_ELEM(v.z, o.z, sqrtf(qq));
      PCEN_ELEM(v.w, o.w, sqrtf(qq));
      res[k] = o;
    }
  } else {
    #pragma unroll
    for (int k = 0; k < QPT; ++k) {
      float4 v = lds4[swz(SEEDQ + tq + k)];
      float4 o;
      PCEN_ELEM(v.x, o.x, exp2f(r * log2f(qq)));
      PCEN_ELEM(v.y, o.y, exp2f(r * log2f(qq)));
      PCEN_ELEM(v.z, o.z, exp2f(r * log2f(qq)));
      PCEN_ELEM(v.w, o.w, exp2f(r * log2f(qq)));
      res[k] = o;
    }
  }
  #undef PCEN_ELEM

  // neighbor seed-reads must finish before in-place overwrite
  __syncthreads();

  #pragma unroll
  for (int k = 0; k < QPT; ++k) lds4[swz(SEEDQ + tq + k)] = res[k];

  __syncthreads();

  // ---- LDS -> global, lane-linear stores ----
  #pragma unroll
  for (int i = 0; i < QPT; ++i) {
    const int p = SEEDQ + i * BLOCK + tid;
    o4[p - SEEDQ] = lds4[swz(p)];
  }
}

extern "C" void kernel_launch(void* const* d_in, const int* in_sizes, int n_in,
                              void* d_out, int out_size, void* d_ws, size_t ws_size,
                              hipStream_t stream) {
  const float* data  = (const float*)d_in[0];
  const float* alpha = (const float*)d_in[1];
  const float* r     = (const float*)d_in[2];
  const float* delta = (const float*)d_in[3];
  float* out = (float*)d_out;

  const int grid = F * TPB;   // 1024 * 4 = 4096 blocks
  pcen_kernel<<<dim3(grid), dim3(BLOCK), 0, stream>>>(data, alpha, r, delta, out);
}

// Round 5
// 25.615 us; speedup vs baseline: 1.1939x; 1.1939x over previous
//
#include <hip/hip_runtime.h>

// PCEN [1, F=1024, T=16384] fp32.
// EMA with S=0.5 decays 2^-k -> 16-sample warmup window, abs err <= 2^-17.
// R5 (= R4 + compile fix): direct scattered global reads (L2 merges; proven
// clean in R1), registers-only compute with native transcendentals, LDS
// transpose on the OUTPUT only (1 barrier), lane-linear nontemporal stores
// via ext_vector_type(4) (HIP_vector_type rejected by the builtin).

static constexpr int F = 1024;
static constexpr int T = 16384;
static constexpr int C = 16;              // time chunk (= warmup window) / thread
static constexpr int BLOCK = 256;
static constexpr int TILE = BLOCK * C;    // 4096 floats per block
static constexpr int QT = TILE / 4;       // 1024 float4 in LDS (16 KB)
static constexpr float EPS = 1e-6f;

typedef float v4f __attribute__((ext_vector_type(4)));

// XOR swizzle on float4 index (involution, bits 0-2 only).
// stride-4 writes and stride-1 reads both land 2 lanes/bank -> free.
__device__ __forceinline__ int swz(int q) { return q ^ ((q >> 3) & 7); }

#if __has_builtin(__builtin_amdgcn_logf)
__device__ __forceinline__ float nlog2(float x) { return __builtin_amdgcn_logf(x); }
#else
__device__ __forceinline__ float nlog2(float x) { return log2f(x); }
#endif
#if __has_builtin(__builtin_amdgcn_exp2f)
__device__ __forceinline__ float nexp2(float x) { return __builtin_amdgcn_exp2f(x); }
#else
__device__ __forceinline__ float nexp2(float x) { return exp2f(x); }
#endif
#if __has_builtin(__builtin_amdgcn_sqrtf)
__device__ __forceinline__ float nsqrt(float x) { return __builtin_amdgcn_sqrtf(x); }
#else
__device__ __forceinline__ float nsqrt(float x) { return sqrtf(x); }
#endif

__global__ __launch_bounds__(BLOCK, 8) void pcen_kernel(
    const float* __restrict__ data,
    const float* __restrict__ alpha_p,
    const float* __restrict__ r_p,
    const float* __restrict__ delta_p,
    float* __restrict__ out)
{
  __shared__ v4f lds4[QT];

  const int tid = threadIdx.x;
  const int bid = blockIdx.x;
  const int f = bid >> 2;                // row (4 blocks per row)
  const int h = bid & 3;                 // tile in row
  const size_t tilebase = (size_t)f * T + (size_t)h * TILE;
  const size_t tbase = tilebase + (size_t)tid * C;

  // ---- seed: EMA over previous 16 samples from m=0 (error <= 2^-17) ----
  float m = 0.0f;
  if ((h | tid) != 0) {
    const v4f* __restrict__ xs =
        reinterpret_cast<const v4f*>(data + tbase - C);
    #pragma unroll
    for (int k = 0; k < 4; ++k) {
      v4f v = xs[k];
      m = 0.5f * (m + v.x);
      m = 0.5f * (m + v.y);
      m = 0.5f * (m + v.z);
      m = 0.5f * (m + v.w);
    }
  }

  const float alpha = alpha_p[0];
  const float r     = r_p[0];
  const float delta = delta_p[0];
  const bool  rhalf = (r == 0.5f);
  const float delta_r = rhalf ? nsqrt(delta) : nexp2(r * nlog2(delta));

  // ---- main chunk: recurrence + pointwise PCEN in registers ----
  const v4f* __restrict__ xm = reinterpret_cast<const v4f*>(data + tbase);
  v4f res[4];

  #define PCEN_ELEM(XX, OO, POW)                        \
    { m = 0.5f * (m + (XX));                            \
      float lgm = nlog2(m + EPS);                       \
      float inv = nexp2(-alpha * lgm);  /* (M+e)^-a */  \
      float qq  = fmaf((XX), inv, delta);               \
      OO = (POW) - delta_r; }

  if (rhalf) {
    #pragma unroll
    for (int k = 0; k < 4; ++k) {
      v4f v = xm[k];
      v4f o;
      PCEN_ELEM(v.x, o.x, nsqrt(qq));
      PCEN_ELEM(v.y, o.y, nsqrt(qq));
      PCEN_ELEM(v.z, o.z, nsqrt(qq));
      PCEN_ELEM(v.w, o.w, nsqrt(qq));
      res[k] = o;
    }
  } else {
    #pragma unroll
    for (int k = 0; k < 4; ++k) {
      v4f v = xm[k];
      v4f o;
      PCEN_ELEM(v.x, o.x, nexp2(r * nlog2(qq)));
      PCEN_ELEM(v.y, o.y, nexp2(r * nlog2(qq)));
      PCEN_ELEM(v.z, o.z, nexp2(r * nlog2(qq)));
      PCEN_ELEM(v.w, o.w, nexp2(r * nlog2(qq)));
      res[k] = o;
    }
  }
  #undef PCEN_ELEM

  // ---- transpose output through LDS, lane-linear nontemporal stores ----
  const int tq = tid * 4;
  #pragma unroll
  for (int k = 0; k < 4; ++k) lds4[swz(tq + k)] = res[k];

  __syncthreads();

  v4f* __restrict__ o4 = reinterpret_cast<v4f*>(out + tilebase);
  #pragma unroll
  for (int i = 0; i < 4; ++i) {
    const int p = i * BLOCK + tid;
    __builtin_nontemporal_store(lds4[swz(p)], o4 + p);
  }
}

extern "C" void kernel_launch(void* const* d_in, const int* in_sizes, int n_in,
                              void* d_out, int out_size, void* d_ws, size_t ws_size,
                              hipStream_t stream) {
  const float* data  = (const float*)d_in[0];
  const float* alpha = (const float*)d_in[1];
  const float* r     = (const float*)d_in[2];
  const float* delta = (const float*)d_in[3];
  float* out = (float*)d_out;

  const int grid = F * (T / TILE);   // 1024 * 4 = 4096 blocks
  pcen_kernel<<<dim3(grid), dim3(BLOCK), 0, stream>>>(data, alpha, r, delta, out);
}

// Round 6
// 24.953 us; speedup vs baseline: 1.2256x; 1.0265x over previous
//
#include <hip/hip_runtime.h>

// PCEN [1, F=1024, T=16384] fp32.
// EMA with S=0.5 decays 2^-k -> 16-sample warmup window, abs err <= 2^-17.
// R6: zero-barrier version.
//  - Seed comes from __shfl_up of the previous lane's chunk-local EMA
//    (bitwise-identical arithmetic to re-reading the window); only wave-lead
//    lanes (tid%64==0) read their seed window from global.
//  - Output transpose is wave-local: each wave owns a private 4 KB LDS slice,
//    so ds_write -> ds_read needs only lgkmcnt (compiler-inserted), no
//    s_barrier. Waves are fully independent -> phases overlap across waves.

static constexpr int F = 1024;
static constexpr int T = 16384;
static constexpr int C = 16;              // time chunk per thread (= window)
static constexpr int BLOCK = 256;
static constexpr int TILE = BLOCK * C;    // 4096 floats per block
static constexpr int QT = TILE / 4;       // 1024 float4 in LDS (16 KB)
static constexpr float EPS = 1e-6f;

typedef float v4f __attribute__((ext_vector_type(4)));

// XOR swizzle on float4 index within a 256-float4 wave slice.
// write q=4l+k (stride 4) and read q=64i+l (stride 1 over lanes): every
// 16-lane group covers each bank-quad exactly twice -> 2-way = free.
__device__ __forceinline__ int swz(int q) { return q ^ ((q >> 3) & 7); }

#if __has_builtin(__builtin_amdgcn_logf)
__device__ __forceinline__ float nlog2(float x) { return __builtin_amdgcn_logf(x); }
#else
__device__ __forceinline__ float nlog2(float x) { return log2f(x); }
#endif
#if __has_builtin(__builtin_amdgcn_exp2f)
__device__ __forceinline__ float nexp2(float x) { return __builtin_amdgcn_exp2f(x); }
#else
__device__ __forceinline__ float nexp2(float x) { return exp2f(x); }
#endif
#if __has_builtin(__builtin_amdgcn_sqrtf)
__device__ __forceinline__ float nsqrt(float x) { return __builtin_amdgcn_sqrtf(x); }
#else
__device__ __forceinline__ float nsqrt(float x) { return sqrtf(x); }
#endif

__global__ __launch_bounds__(BLOCK, 8) void pcen_kernel(
    const float* __restrict__ data,
    const float* __restrict__ alpha_p,
    const float* __restrict__ r_p,
    const float* __restrict__ delta_p,
    float* __restrict__ out)
{
  __shared__ v4f lds4[QT];

  const int tid = threadIdx.x;
  const int bid = blockIdx.x;
  const int f = bid >> 2;                // row (4 blocks per row)
  const int h = bid & 3;                 // tile in row
  const size_t tilebase = (size_t)f * T + (size_t)h * TILE;
  const size_t tbase = tilebase + (size_t)tid * C;

  // ---- load own chunk (kept in registers) ----
  const v4f* __restrict__ xm = reinterpret_cast<const v4f*>(data + tbase);
  v4f v0 = xm[0], v1 = xm[1], v2 = xm[2], v3 = xm[3];

  // ---- chunk-local EMA from zero (this IS the next lane's seed) ----
  float m0 = 0.0f;
  #define ESTEP(X) m0 = 0.5f * (m0 + (X));
  ESTEP(v0.x) ESTEP(v0.y) ESTEP(v0.z) ESTEP(v0.w)
  ESTEP(v1.x) ESTEP(v1.y) ESTEP(v1.z) ESTEP(v1.w)
  ESTEP(v2.x) ESTEP(v2.y) ESTEP(v2.z) ESTEP(v2.w)
  ESTEP(v3.x) ESTEP(v3.y) ESTEP(v3.z) ESTEP(v3.w)
  #undef ESTEP

  float seed = __shfl_up(m0, 1, 64);
  if ((tid & 63) == 0) {                 // wave-lead: cross-wave boundary
    float s = 0.0f;
    if ((h | tid) != 0) {                // (h==0 && tid==0) -> EMA starts at 0
      const v4f* __restrict__ xs =
          reinterpret_cast<const v4f*>(data + tbase - C);
      #pragma unroll
      for (int k = 0; k < 4; ++k) {
        v4f v = xs[k];
        s = 0.5f * (s + v.x);
        s = 0.5f * (s + v.y);
        s = 0.5f * (s + v.z);
        s = 0.5f * (s + v.w);
      }
    }
    seed = s;
  }

  const float alpha = alpha_p[0];
  const float r     = r_p[0];
  const float delta = delta_p[0];
  const bool  rhalf = (r == 0.5f);
  const float delta_r = rhalf ? nsqrt(delta) : nexp2(r * nlog2(delta));

  // ---- recurrence + pointwise PCEN in registers ----
  float m = seed;
  v4f res[4];

  #define PCEN_ELEM(XX, OO, POW)                        \
    { m = 0.5f * (m + (XX));                            \
      float lgm = nlog2(m + EPS);                       \
      float inv = nexp2(-alpha * lgm);  /* (M+e)^-a */  \
      float qq  = fmaf((XX), inv, delta);               \
      OO = (POW) - delta_r; }

  #define PCEN_VEC(V, K, POWX, POWY, POWZ, POWW)        \
    { v4f o;                                            \
      PCEN_ELEM(V.x, o.x, POWX);                        \
      PCEN_ELEM(V.y, o.y, POWY);                        \
      PCEN_ELEM(V.z, o.z, POWZ);                        \
      PCEN_ELEM(V.w, o.w, POWW);                        \
      res[K] = o; }

  if (rhalf) {
    PCEN_VEC(v0, 0, nsqrt(qq), nsqrt(qq), nsqrt(qq), nsqrt(qq))
    PCEN_VEC(v1, 1, nsqrt(qq), nsqrt(qq), nsqrt(qq), nsqrt(qq))
    PCEN_VEC(v2, 2, nsqrt(qq), nsqrt(qq), nsqrt(qq), nsqrt(qq))
    PCEN_VEC(v3, 3, nsqrt(qq), nsqrt(qq), nsqrt(qq), nsqrt(qq))
  } else {
    PCEN_VEC(v0, 0, nexp2(r * nlog2(qq)), nexp2(r * nlog2(qq)),
                    nexp2(r * nlog2(qq)), nexp2(r * nlog2(qq)))
    PCEN_VEC(v1, 1, nexp2(r * nlog2(qq)), nexp2(r * nlog2(qq)),
                    nexp2(r * nlog2(qq)), nexp2(r * nlog2(qq)))
    PCEN_VEC(v2, 2, nexp2(r * nlog2(qq)), nexp2(r * nlog2(qq)),
                    nexp2(r * nlog2(qq)), nexp2(r * nlog2(qq)))
    PCEN_VEC(v3, 3, nexp2(r * nlog2(qq)), nexp2(r * nlog2(qq)),
                    nexp2(r * nlog2(qq)), nexp2(r * nlog2(qq)))
  }
  #undef PCEN_VEC
  #undef PCEN_ELEM

  // ---- wave-local transpose through private LDS slice (no s_barrier) ----
  const int l  = tid & 63;               // lane
  const int wq = (tid >> 6) * 256;       // wave's float4 base in LDS

  #pragma unroll
  for (int k = 0; k < 4; ++k) lds4[wq + swz(l * 4 + k)] = res[k];

  __builtin_amdgcn_wave_barrier();       // no reorder; lgkmcnt auto-inserted

  v4f* __restrict__ o4 =
      reinterpret_cast<v4f*>(out + tilebase) + (size_t)(tid >> 6) * 256;
  #pragma unroll
  for (int i = 0; i < 4; ++i) {
    const int p = i * 64 + l;
    __builtin_nontemporal_store(lds4[wq + swz(p)], o4 + p);
  }
}

extern "C" void kernel_launch(void* const* d_in, const int* in_sizes, int n_in,
                              void* d_out, int out_size, void* d_ws, size_t ws_size,
                              hipStream_t stream) {
  const float* data  = (const float*)d_in[0];
  const float* alpha = (const float*)d_in[1];
  const float* r     = (const float*)d_in[2];
  const float* delta = (const float*)d_in[3];
  float* out = (float*)d_out;

  const int grid = F * (T / TILE);   // 1024 * 4 = 4096 blocks
  pcen_kernel<<<dim3(grid), dim3(BLOCK), 0, stream>>>(data, alpha, r, delta, out);
}